// Round 9
// baseline (3369.492 us; speedup 1.0000x reference)
//
#include <hip/hip_runtime.h>
#include <cstdint>
#include <math.h>

#define NB_B   16
#define NB_T   511
#define NB_S   512
#define NB_OBS 60
#define NB_D   1024
#define NB_H   16
#define NB_L   8
#define NB_DFF 4096
#define NB_HID 100
#define NB_OUT 30
#define NB_M   8192   // B*S rows
#define QKV_S  3072   // merged qkv row stride

typedef __attribute__((ext_vector_type(8))) short  short8;
typedef __attribute__((ext_vector_type(4))) short  short4v;
typedef __attribute__((ext_vector_type(4))) float  f32x4;
typedef __attribute__((ext_vector_type(8))) __bf16 bf16x8;

template <int N_> struct ic { static constexpr int v = N_; };

__device__ __forceinline__ short f2bf(float f) {
  union { float f; unsigned u; } a; a.f = f;
  unsigned u = a.u + 0x7fffu + ((a.u >> 16) & 1u);   // RTNE
  return (short)(u >> 16);
}

__device__ __forceinline__ void load_lds16(const void* g, void* l) {
  __builtin_amdgcn_global_load_lds(
      (__attribute__((address_space(1))) unsigned int*)(uintptr_t)g,
      (__attribute__((address_space(3))) unsigned int*)(unsigned)(uintptr_t)l,
      16, 0, 0);
}

__device__ __forceinline__ f32x4 mfma16(short8 a, short8 b, f32x4 c) {
  return __builtin_amdgcn_mfma_f32_16x16x32_bf16(
      __builtin_bit_cast(bf16x8, a), __builtin_bit_cast(bf16x8, b), c, 0, 0, 0);
}

// gelu via sigmoid form of tanh approx; |err vs exact| <= ~3e-4
__device__ __forceinline__ float gelu_fast(float v) {
  const float t = 1.5957691216057308f * (v + 0.044715f * v * v * v);
  const float e = __expf(fminf(t, 30.f));
  return v * (e / (e + 1.f));
}

// ---------------------------------------------------------------------------
// Weight transpose + fp32->bf16: src (R,C) fp32 -> dst (C,R) bf16 bits
// ---------------------------------------------------------------------------
__global__ __launch_bounds__(256) void tconv2_kernel(
    const float* __restrict__ src, short* __restrict__ dst,
    int R, int C, size_t sstride, size_t dstride) {
  __shared__ float t[64][65];
  const float* s0 = src + blockIdx.z * sstride;
  short* d0 = dst + blockIdx.z * dstride;
  const int c0 = blockIdx.x * 64, r0 = blockIdx.y * 64;
#pragma unroll
  for (int i = 0; i < 4; i++) {
    const int idx = threadIdx.x + i * 256;
    const int r = idx >> 4, c4 = (idx & 15) * 4;
    const float4 v = *(const float4*)&s0[(size_t)(r0 + r) * C + c0 + c4];
    t[r][c4 + 0] = v.x; t[r][c4 + 1] = v.y; t[r][c4 + 2] = v.z; t[r][c4 + 3] = v.w;
  }
  __syncthreads();
#pragma unroll
  for (int i = 0; i < 2; i++) {
    const int idx = threadIdx.x + i * 256;
    const int c = idx >> 3, g = (idx & 7) * 8;
    short8 o;
#pragma unroll
    for (int j = 0; j < 8; j++) o[j] = f2bf(t[g + j][c]);
    *(short8*)&d0[(size_t)(c0 + c) * R + r0 + g] = o;
  }
}

// ---------------------------------------------------------------------------
// Head weight prep + concat qkv bias
// ---------------------------------------------------------------------------
__global__ __launch_bounds__(256) void whead_prep(
    const float* __restrict__ Wh1, const float* __restrict__ bh1,
    short* __restrict__ Wh1t, float* __restrict__ bh1p) {
  const int idx = blockIdx.x * 256 + threadIdx.x;
  const int n = idx >> 10, k = idx & 1023;
  Wh1t[idx] = (n < NB_HID) ? f2bf(Wh1[k * NB_HID + n]) : (short)0;
  if (idx < 128) bh1p[idx] = (idx < NB_HID) ? bh1[idx] : 0.f;
}

__global__ __launch_bounds__(256) void qkvbias_prep(
    const float* __restrict__ bq, const float* __restrict__ bk,
    const float* __restrict__ bv, float* __restrict__ outb) {
  const int idx = blockIdx.x * 256 + threadIdx.x;   // 0 .. 8*3072-1
  const int l = idx / QKV_S, r = idx - l * QKV_S;
  const int z = r >> 10, c = r & 1023;
  const float* src = (z == 0) ? bq : ((z == 1) ? bk : bv);
  outb[idx] = src[l * NB_D + c];
}

// ---------------------------------------------------------------------------
// Token + positional embedding, 8 rows/block
// ---------------------------------------------------------------------------
__global__ __launch_bounds__(256) void embed2_kernel(
    const float* __restrict__ states, const float* __restrict__ goals,
    const float* __restrict__ Wtok, const float* __restrict__ btok,
    const float* __restrict__ pos, float* __restrict__ x) {
  const int r0 = blockIdx.x * 8;
  __shared__ float tok[8][NB_OBS];
  for (int idx = threadIdx.x; idx < 8 * NB_OBS; idx += 256) {
    const int r = idx / NB_OBS, o = idx - r * NB_OBS;
    const int row = r0 + r, b = row >> 9, s = row & 511;
    tok[r][o] = (s == 0) ? goals[b * NB_OBS + o]
                         : states[((size_t)b * NB_T + (s - 1)) * NB_OBS + o];
  }
  __syncthreads();
#pragma unroll
  for (int i = 0; i < 4; i++) {
    const int d = threadIdx.x + i * 256;
    float acc[8];
#pragma unroll
    for (int r = 0; r < 8; r++) acc[r] = 0.f;
    for (int o = 0; o < NB_OBS; o++) {
      const float wv = Wtok[o * NB_D + d];
#pragma unroll
      for (int r = 0; r < 8; r++) acc[r] += tok[r][o] * wv;
    }
    const float bt = btok[d];
#pragma unroll
    for (int r = 0; r < 8; r++) {
      const int row = r0 + r, s = row & 511;
      x[(size_t)row * NB_D + d] = acc[r] + bt + pos[(size_t)s * NB_D + d];
    }
  }
}

// ---------------------------------------------------------------------------
// Wave-per-row LayerNorm: 4 rows/block, no LDS, no barriers.
// ---------------------------------------------------------------------------
template <typename OutT>
__global__ __launch_bounds__(256) void ln_wave(
    const float* __restrict__ xin, const float* __restrict__ gam,
    const float* __restrict__ bet, OutT* __restrict__ outp) {
  const int row = blockIdx.x * 4 + (threadIdx.x >> 6);
  const int lane = threadIdx.x & 63;
  const float4* src = (const float4*)(xin + (size_t)row * NB_D);
  float4 v[4];
  float s = 0.f, s2 = 0.f;
#pragma unroll
  for (int i = 0; i < 4; i++) {
    v[i] = src[lane + 64 * i];
    s += v[i].x + v[i].y + v[i].z + v[i].w;
    s2 += v[i].x * v[i].x + v[i].y * v[i].y + v[i].z * v[i].z + v[i].w * v[i].w;
  }
#pragma unroll
  for (int o = 32; o; o >>= 1) {
    s += __shfl_xor(s, o, 64);
    s2 += __shfl_xor(s2, o, 64);
  }
  const float mean = s * (1.f / NB_D);
  const float var = s2 * (1.f / NB_D) - mean * mean;
  const float rs = rsqrtf(var + 1e-5f);
#pragma unroll
  for (int i = 0; i < 4; i++) {
    const float4 g4 = ((const float4*)gam)[lane + 64 * i];
    const float4 b4 = ((const float4*)bet)[lane + 64 * i];
    const float o0 = (v[i].x - mean) * rs * g4.x + b4.x;
    const float o1 = (v[i].y - mean) * rs * g4.y + b4.y;
    const float o2 = (v[i].z - mean) * rs * g4.z + b4.z;
    const float o3 = (v[i].w - mean) * rs * g4.w + b4.w;
    if constexpr (sizeof(OutT) == 2) {
      short4v r = {f2bf(o0), f2bf(o1), f2bf(o2), f2bf(o3)};
      *(short4v*)((short*)outp + (size_t)row * NB_D + (lane + 64 * i) * 4) = r;
    } else {
      ((float4*)((float*)outp + (size_t)row * NB_D))[lane + 64 * i] =
          make_float4(o0, o1, o2, o3);
    }
  }
}

// ---------------------------------------------------------------------------
// GEMM v4b: the validated 3-buffer / counted-vmcnt / 1-barrier-per-K-tile
// pipeline, tile sizes chosen for >=3 co-resident blocks/CU (m114 mechanism:
// cross-block overlap covers barrier drains).
//   BM=128: LDS 48 KiB -> 3 blocks/CU (QKV grid 1536, MLP1 grid 2048)
//   BM=64 : LDS 36 KiB -> 4 blocks/CU (proj/MLP2 grid 1024)
// BN=128, BK=32, 256 threads (4 waves 2Mx2N, per-wave (BM/2)x64).
// L = 2 + BM/64 loads/thread/K-tile; gate vmcnt(L) keeps next tile in flight.
// XOR 16B-slot swizzle (pre-swizzled global src, rule #21); T1 bijective XCD
// chunking, bm-outer/bn-inner.
// ---------------------------------------------------------------------------
template <int BM, int N, int K, int ACT, bool RESID, typename OutT>
__global__ __launch_bounds__(256, 4) void gemmv4b(
    const short* __restrict__ A, const short* __restrict__ Bt,
    const float* __restrict__ bias, const float* __restrict__ resid,
    OutT* __restrict__ C) {
  constexpr int MI = BM / 32;
  constexpr int NK = K / 32;
  constexpr int NBN = N / 128;
  constexpr int NWG = (NB_M / BM) * NBN;
  constexpr int QC = NWG / 8;
  constexpr int L = 2 + BM / 64;
  constexpr int SA = BM * 32;

  __shared__ short As[3][SA];
  __shared__ short Bs[3][128 * 32];

  int wg = blockIdx.x;
  wg = (wg & 7) * QC + (wg >> 3);       // bijective XCD chunking
  const int bm = (wg / NBN) * BM;       // bm-outer, bn-inner within chunk
  const int bn = (wg % NBN) * 128;

  const int tid = threadIdx.x;
  const int w = tid >> 6, lane = tid & 63;
  const int wm = w >> 1, wn = w & 1;
  const int rr = lane & 15, sg = lane >> 4;
  const int lrow = lane >> 2, lslot = lane & 3;
  const int sslot = lslot ^ ((lrow >> 1) & 3);

  const short* Asrc = A + (size_t)(bm + (w * 16 + lrow) % BM) * K + sslot * 8;
  const short* Bsrc = Bt + (size_t)(bn + w * 16 + lrow) * K + sslot * 8;
  short* Adst = &As[0][(w * 512) % SA];
  short* Bdst = &Bs[0][w * 512];

  const int ar = wm * (BM / 2) + rr;
  const int br = wn * 64 + rr;
  const int aoff = ar * 32 + ((sg ^ ((ar >> 1) & 3)) * 8);
  const int boff = br * 32 + ((sg ^ ((br >> 1) & 3)) * 8);

  f32x4 acc[MI][4];
#pragma unroll
  for (int i = 0; i < MI; i++)
#pragma unroll
    for (int j = 0; j < 4; j++) acc[i][j] = f32x4{0.f, 0.f, 0.f, 0.f};

  auto stage = [&](int sb, int k0) {
    load_lds16(Bsrc + k0,                  Bdst + sb * 4096);
    load_lds16(Bsrc + (size_t)64 * K + k0, Bdst + sb * 4096 + 2048);
    if constexpr (BM == 64) {
      // 4 waves cover all 64 rows once (w*16+lrow mod 64 spans 0..63 twice;
      // waves 0,1 and 2,3 write the same rows -> restrict to w<2 illegal in
      // wave-uniform staging; instead both pairs write identical data (safe).
      load_lds16(Asrc + k0, Adst + sb * SA);
    } else {
#pragma unroll
      for (int c = 0; c < BM / 64; c++)
        load_lds16(Asrc + (size_t)(c * 64) * K + k0, Adst + sb * SA + c * 2048);
    }
  };

  auto gate = [&]() {
    if constexpr (L == 3)      asm volatile("s_waitcnt vmcnt(3)" ::: "memory");
    else if constexpr (L == 4) asm volatile("s_waitcnt vmcnt(4)" ::: "memory");
    else                       asm volatile("s_waitcnt vmcnt(6)" ::: "memory");
  };

  stage(0, 0);
  stage(1, 32);
  gate();
  __builtin_amdgcn_s_barrier();

  auto ktile = [&](auto BUFC, auto SBUFC, int t) {
    constexpr int BUF = decltype(BUFC)::v;
    constexpr int SBUF = decltype(SBUFC)::v;
    const short* Ab = &As[BUF][0];
    const short* Bb = &Bs[BUF][0];
    if (t + 2 < NK) stage(SBUF, (t + 2) * 32);
    short8 a[MI], b[4];
#pragma unroll
    for (int i = 0; i < MI; i++) a[i] = *(const short8*)(Ab + aoff + i * 512);
#pragma unroll
    for (int j = 0; j < 4; j++) b[j] = *(const short8*)(Bb + boff + j * 512);
    __builtin_amdgcn_s_setprio(1);
#pragma unroll
    for (int i = 0; i < MI; i++)
#pragma unroll
      for (int j = 0; j < 4; j++) acc[i][j] = mfma16(a[i], b[j], acc[i][j]);
    __builtin_amdgcn_s_setprio(0);
    if (t + 2 < NK)      gate();
    else if (t + 1 < NK) asm volatile("s_waitcnt vmcnt(0)" ::: "memory");
    __builtin_amdgcn_s_barrier();
  };

  int t = 0;
#pragma unroll 1
  for (; t + 3 <= NK; t += 3) {
    ktile(ic<0>{}, ic<2>{}, t);
    ktile(ic<1>{}, ic<0>{}, t + 1);
    ktile(ic<2>{}, ic<1>{}, t + 2);
  }
  if constexpr (NK % 3 >= 1) ktile(ic<0>{}, ic<2>{}, NK - NK % 3);
  if constexpr (NK % 3 >= 2) ktile(ic<1>{}, ic<0>{}, NK - NK % 3 + 1);

  const int col0 = bn + wn * 64 + rr;
  float bv[4];
#pragma unroll
  for (int j = 0; j < 4; j++) bv[j] = bias[col0 + j * 16];
#pragma unroll
  for (int i = 0; i < MI; i++) {
#pragma unroll
    for (int q = 0; q < 4; q++) {
      const size_t row = bm + wm * (BM / 2) + i * 16 + sg * 4 + q;
      float v0 = acc[i][0][q] + bv[0];
      float v1 = acc[i][1][q] + bv[1];
      float v2 = acc[i][2][q] + bv[2];
      float v3 = acc[i][3][q] + bv[3];
      if constexpr (RESID) {
        const float* rrow = resid + row * N + col0;
        v0 += rrow[0]; v1 += rrow[16]; v2 += rrow[32]; v3 += rrow[48];
      }
      if constexpr (ACT == 1) {
        v0 = gelu_fast(v0); v1 = gelu_fast(v1);
        v2 = gelu_fast(v2); v3 = gelu_fast(v3);
      }
      OutT* crow = C + row * N + col0;
      if constexpr (sizeof(OutT) == 2) {
        crow[0] = (OutT)f2bf(v0); crow[16] = (OutT)f2bf(v1);
        crow[32] = (OutT)f2bf(v2); crow[48] = (OutT)f2bf(v3);
      } else {
        crow[0] = v0; crow[16] = v1; crow[32] = v2; crow[48] = v3;
      }
    }
  }
}

// ---------------------------------------------------------------------------
// Head GEMM (N=128): m97 structure, runtime N/K (tiny, one shape).
// ---------------------------------------------------------------------------
template <int ACT, bool RESID, typename OutT>
__global__ __launch_bounds__(256) void gemm_bt(
    const short* __restrict__ A, const short* __restrict__ Bt,
    const float* __restrict__ bias, const float* __restrict__ resid,
    OutT* __restrict__ C, int N, int K) {
  __shared__ short As[128][32];
  __shared__ short Bs[128][32];
  const int bm = blockIdx.y * 128, bn = blockIdx.x * 128;
  const int tid = threadIdx.x;
  const int w = tid >> 6, lane = tid & 63;
  const int wr = (w >> 1) * 64, wc = (w & 1) * 64;
  const int rr = lane & 15, sg = lane >> 4;

  f32x4 acc[4][4];
#pragma unroll
  for (int i = 0; i < 4; i++)
#pragma unroll
    for (int j = 0; j < 4; j++) acc[i][j] = f32x4{0.f, 0.f, 0.f, 0.f};

  const int srow0 = w * 32 + (lane >> 2);
  const int sslot = lane & 3;

  for (int k0 = 0; k0 < K; k0 += 32) {
    __syncthreads();
#pragma unroll
    for (int inst = 0; inst < 2; inst++) {
      const int r = srow0 + inst * 16;
      const int sl = sslot ^ ((r >> 1) & 3);
      load_lds16(A + (size_t)(bm + r) * K + k0 + sl * 8, &As[w * 32 + inst * 16][0]);
      load_lds16(Bt + (size_t)(bn + r) * K + k0 + sl * 8, &Bs[w * 32 + inst * 16][0]);
    }
    __syncthreads();
    short8 a[4], b[4];
#pragma unroll
    for (int i = 0; i < 4; i++) {
      const int r = wr + i * 16 + rr;
      a[i] = *(const short8*)&As[r][(sg ^ ((r >> 1) & 3)) * 8];
      const int c = wc + i * 16 + rr;
      b[i] = *(const short8*)&Bs[c][(sg ^ ((c >> 1) & 3)) * 8];
    }
#pragma unroll
    for (int i = 0; i < 4; i++)
#pragma unroll
      for (int j = 0; j < 4; j++) acc[i][j] = mfma16(a[i], b[j], acc[i][j]);
  }

#pragma unroll
  for (int j = 0; j < 4; j++) {
    const int col = bn + wc + j * 16 + rr;
    const float bv = bias[col];
#pragma unroll
    for (int i = 0; i < 4; i++) {
#pragma unroll
      for (int q = 0; q < 4; q++) {
        const int row = bm + wr + i * 16 + sg * 4 + q;
        float v = acc[i][j][q] + bv;
        if constexpr (RESID) v += resid[(size_t)row * N + col];
        if constexpr (ACT == 1) v = gelu_fast(v);
        if constexpr (ACT == 2) v = v / (1.f + __expf(-v));
        if constexpr (sizeof(OutT) == 2) C[(size_t)row * N + col] = (OutT)f2bf(v);
        else C[(size_t)row * N + col] = v;
      }
    }
  }
}

// ---------------------------------------------------------------------------
// Fused causal flash attention; qkv is merged (M, 3072): q|k|v per row.
// ---------------------------------------------------------------------------
__global__ __launch_bounds__(256) void attn_kernel(
    const short* __restrict__ qkv, short* __restrict__ out) {
  const int qt = blockIdx.x, hh = blockIdx.y, bb = blockIdx.z;
  const int tid = threadIdx.x;
  const int w = tid >> 6, lane = tid & 63;
  const int rr = lane & 15, sg = lane >> 4;

  __shared__ short Ks[64][64];
  __shared__ short Vt[64][64];
  __shared__ short Ps[4][16][64];

  short8 qf[2];
  {
    const size_t qrow = (size_t)bb * NB_S + qt * 64 + w * 16 + rr;
#pragma unroll
    for (int ks = 0; ks < 2; ks++)
      qf[ks] = *(const short8*)&qkv[qrow * QKV_S + hh * 64 + ks * 32 + sg * 8];
  }

  float mrow[4], lrow[4];
  f32x4 o[4];
#pragma unroll
  for (int j = 0; j < 4; j++) { mrow[j] = -INFINITY; lrow[j] = 0.f; }
#pragma unroll
  for (int nb = 0; nb < 4; nb++) o[nb] = f32x4{0.f, 0.f, 0.f, 0.f};

  for (int kt = 0; kt <= qt; kt++) {
    __syncthreads();
    {
      const int p = lane & 7;
#pragma unroll
      for (int inst = 0; inst < 2; inst++) {
        const int r = w * 16 + inst * 8 + (lane >> 3);
        const int sl = p ^ (r & 7);
        load_lds16(qkv + ((size_t)bb * NB_S + kt * 64 + r) * QKV_S + 1024 + hh * 64 + sl * 8,
                   &Ks[w * 16 + inst * 8][0]);
      }
    }
    {
#pragma unroll
      for (int cc = 0; cc < 2; cc++) {
        const int c = tid * 2 + cc;
        const int sk = c >> 3, sl = c & 7;
        short8 vv = *(const short8*)&qkv[((size_t)bb * NB_S + kt * 64 + sk) * QKV_S + 2048 + hh * 64 + sl * 8];
        const int ss = sk >> 3;
#pragma unroll
        for (int j = 0; j < 8; j++) {
          const int dh = sl * 8 + j;
          Vt[dh][(ss ^ (dh & 7)) * 8 + (sk & 7)] = vv[j];
        }
      }
    }
    __syncthreads();

    f32x4 sf[4];
#pragma unroll
    for (int nb = 0; nb < 4; nb++) sf[nb] = f32x4{0.f, 0.f, 0.f, 0.f};
#pragma unroll
    for (int ks = 0; ks < 2; ks++) {
#pragma unroll
      for (int nb = 0; nb < 4; nb++) {
        const int ck = nb * 16 + rr;
        short8 kf = *(const short8*)&Ks[ck][((ks * 4 + sg) ^ (ck & 7)) * 8];
        sf[nb] = mfma16(qf[ks], kf, sf[nb]);
      }
    }
    const int rbase = qt * 64 + w * 16 + sg * 4;
    float pmax[4] = {-INFINITY, -INFINITY, -INFINITY, -INFINITY};
#pragma unroll
    for (int nb = 0; nb < 4; nb++) {
      const int cg = kt * 64 + nb * 16 + rr;
#pragma unroll
      for (int j = 0; j < 4; j++) {
        float sv = sf[nb][j] * 0.125f;
        if (cg > rbase + j) sv = -INFINITY;
        sf[nb][j] = sv;
        pmax[j] = fmaxf(pmax[j], sv);
      }
    }
#pragma unroll
    for (int o1 = 1; o1 < 16; o1 <<= 1)
#pragma unroll
      for (int j = 0; j < 4; j++)
        pmax[j] = fmaxf(pmax[j], __shfl_xor(pmax[j], o1, 64));

    float resc[4], psum[4];
#pragma unroll
    for (int j = 0; j < 4; j++) {
      const float mn = fmaxf(mrow[j], pmax[j]);
      resc[j] = __expf(mrow[j] - mn);
      mrow[j] = mn;
      psum[j] = 0.f;
    }
#pragma unroll
    for (int nb = 0; nb < 4; nb++)
#pragma unroll
      for (int j = 0; j < 4; j++) {
        const float p = __expf(sf[nb][j] - mrow[j]);
        sf[nb][j] = p;
        psum[j] += p;
      }
#pragma unroll
    for (int o1 = 1; o1 < 16; o1 <<= 1)
#pragma unroll
      for (int j = 0; j < 4; j++) psum[j] += __shfl_xor(psum[j], o1, 64);
#pragma unroll
    for (int j = 0; j < 4; j++) lrow[j] = lrow[j] * resc[j] + psum[j];
#pragma unroll
    for (int nb = 0; nb < 4; nb++)
#pragma unroll
      for (int j = 0; j < 4; j++) o[nb][j] *= resc[j];

#pragma unroll
    for (int nb = 0; nb < 4; nb++) {
      const int ck = nb * 16 + rr;
      const int ss = ck >> 3;
#pragma unroll
      for (int j = 0; j < 4; j++) {
        const int rq = sg * 4 + j;
        Ps[w][rq][(ss ^ (rq & 7)) * 8 + (ck & 7)] = f2bf(sf[nb][j]);
      }
    }
#pragma unroll
    for (int ks = 0; ks < 2; ks++) {
      short8 pf = *(const short8*)&Ps[w][rr][((ks * 4 + sg) ^ (rr & 7)) * 8];
#pragma unroll
      for (int nb = 0; nb < 4; nb++) {
        const int dh = nb * 16 + rr;
        short8 vf = *(const short8*)&Vt[dh][((ks * 4 + sg) ^ (dh & 7)) * 8];
        o[nb] = mfma16(pf, vf, o[nb]);
      }
    }
  }

  {
    const size_t orow0 = (size_t)bb * NB_S + qt * 64 + w * 16;
#pragma unroll
    for (int nb = 0; nb < 4; nb++)
#pragma unroll
      for (int j = 0; j < 4; j++) {
        const float v = o[nb][j] / lrow[j];
        out[(orow0 + sg * 4 + j) * NB_D + hh * 64 + nb * 16 + rr] = f2bf(v);
      }
  }
}

// ---------------------------------------------------------------------------
// Head stage 2: out(8176,30) = hbuf(.,100) @ Wh2(100,30) + bh2, fp32.
// ---------------------------------------------------------------------------
__global__ __launch_bounds__(256) void head2_kernel(
    const float* __restrict__ hbuf, const float* __restrict__ Wh2,
    const float* __restrict__ bh2, float* __restrict__ outp) {
  __shared__ float hs[8][NB_HID];
  const int g0 = blockIdx.x * 8;
  for (int idx = threadIdx.x; idx < 8 * NB_HID; idx += 256) {
    const int r = idx / NB_HID, k = idx - r * NB_HID;
    const int gt = g0 + r;
    const int b = gt / NB_T, tt = gt - b * NB_T;
    hs[r][k] = hbuf[(size_t)(b * NB_S + 1 + tt) * 128 + k];
  }
  __syncthreads();
  const int r = threadIdx.x >> 5, c = threadIdx.x & 31;
  if (c < NB_OUT) {
    float acc = bh2[c];
#pragma unroll
    for (int k = 0; k < NB_HID; k++) acc += hs[r][k] * Wh2[k * NB_OUT + c];
    outp[(size_t)(g0 + r) * NB_OUT + c] = acc;
  }
}

// ---------------------------------------------------------------------------
extern "C" void kernel_launch(void* const* d_in, const int* in_sizes, int n_in,
                              void* d_out, int out_size, void* d_ws, size_t ws_size,
                              hipStream_t stream) {
  const float* states = (const float*)d_in[0];
  const float* goals  = (const float*)d_in[1];
  const float* Wtok   = (const float*)d_in[2];
  const float* btok   = (const float*)d_in[3];
  const float* pos    = (const float*)d_in[4];
  const float* ln1_g  = (const float*)d_in[5];
  const float* ln1_b  = (const float*)d_in[6];
  const float* Wq     = (const float*)d_in[7];
  const float* bq     = (const float*)d_in[8];
  const float* Wk     = (const float*)d_in[9];
  const float* bk     = (const float*)d_in[10];
  const float* Wv     = (const float*)d_in[11];
  const float* bv     = (const float*)d_in[12];
  const float* Wp     = (const float*)d_in[13];
  const float* bp     = (const float*)d_in[14];
  const float* ln2_g  = (const float*)d_in[15];
  const float* ln2_b  = (const float*)d_in[16];
  const float* Wm1    = (const float*)d_in[17];
  const float* bm1    = (const float*)d_in[18];
  const float* Wm2    = (const float*)d_in[19];
  const float* bm2    = (const float*)d_in[20];
  const float* lnf_g  = (const float*)d_in[21];
  const float* lnf_b  = (const float*)d_in[22];
  const float* Wh1    = (const float*)d_in[23];
  const float* bh1    = (const float*)d_in[24];
  const float* Wh2    = (const float*)d_in[25];
  const float* bh2    = (const float*)d_in[26];

  char* wsp = (char*)d_ws;
  size_t off = 0;
  auto carve = [&](size_t bytes) -> char* {
    char* p = wsp + off;
    off += (bytes + 1023) & ~(size_t)1023;
    return p;
  };
  short* Wqkv_t = (short*)carve((size_t)NB_L * 3 * NB_D * NB_D * 2);  // (l, 3072, 1024)
  short* Wp_t   = (short*)carve((size_t)NB_L * NB_D * NB_D * 2);
  short* Wm1_t  = (short*)carve((size_t)NB_L * NB_DFF * NB_D * 2);
  short* Wm2_t  = (short*)carve((size_t)NB_L * NB_D * NB_DFF * 2);
  float* x      = (float*)carve((size_t)NB_M * NB_D * 4);
  short* h      = (short*)carve((size_t)NB_M * NB_D * 2);
  short* qkvb   = (short*)carve((size_t)NB_M * QKV_S * 2);
  short* mlp    = (short*)carve((size_t)NB_M * NB_DFF * 2);
  short* Wh1t   = (short*)carve((size_t)128 * NB_D * 2);
  float* bh1p   = (float*)carve(128 * 4);
  float* bqkv   = (float*)carve((size_t)NB_L * QKV_S * 4);
  short* attout = mlp;           // alias: dead before mlp is written
  float* hbuf   = (float*)qkvb;  // alias: qkv dead after last attention

  const dim3 thr(256);
  const size_t DD = (size_t)NB_D * NB_D;
  const size_t DF = (size_t)NB_D * NB_DFF;

  tconv2_kernel<<<dim3(16, 16, NB_L), thr, 0, stream>>>(Wq, Wqkv_t + 0 * DD, NB_D, NB_D, DD, 3 * DD);
  tconv2_kernel<<<dim3(16, 16, NB_L), thr, 0, stream>>>(Wk, Wqkv_t + 1 * DD, NB_D, NB_D, DD, 3 * DD);
  tconv2_kernel<<<dim3(16, 16, NB_L), thr, 0, stream>>>(Wv, Wqkv_t + 2 * DD, NB_D, NB_D, DD, 3 * DD);
  tconv2_kernel<<<dim3(16, 16, NB_L), thr, 0, stream>>>(Wp, Wp_t, NB_D, NB_D, DD, DD);
  tconv2_kernel<<<dim3(64, 16, NB_L), thr, 0, stream>>>(Wm1, Wm1_t, NB_D, NB_DFF, DF, DF);
  tconv2_kernel<<<dim3(16, 64, NB_L), thr, 0, stream>>>(Wm2, Wm2_t, NB_DFF, NB_D, DF, DF);
  whead_prep<<<512, thr, 0, stream>>>(Wh1, bh1, Wh1t, bh1p);
  qkvbias_prep<<<96, thr, 0, stream>>>(bq, bk, bv, bqkv);

  embed2_kernel<<<NB_M / 8, thr, 0, stream>>>(states, goals, Wtok, btok, pos, x);

  for (int l = 0; l < NB_L; l++) {
    ln_wave<short><<<NB_M / 4, thr, 0, stream>>>(x, ln1_g + l * NB_D, ln1_b + l * NB_D, h);
    gemmv4b<128, QKV_S, NB_D, 0, false, short><<<1536, thr, 0, stream>>>(
        h, Wqkv_t + (size_t)l * 3 * DD, bqkv + (size_t)l * QKV_S, nullptr, qkvb);
    attn_kernel<<<dim3(NB_S / 64, NB_H, NB_B), thr, 0, stream>>>(qkvb, attout);
    gemmv4b<64, NB_D, NB_D, 0, true, float><<<1024, thr, 0, stream>>>(
        attout, Wp_t + (size_t)l * DD, bp + l * NB_D, x, x);
    ln_wave<short><<<NB_M / 4, thr, 0, stream>>>(x, ln2_g + l * NB_D, ln2_b + l * NB_D, h);
    gemmv4b<128, NB_DFF, NB_D, 1, false, short><<<2048, thr, 0, stream>>>(
        h, Wm1_t + (size_t)l * DF, bm1 + l * NB_DFF, nullptr, mlp);
    gemmv4b<64, NB_D, NB_DFF, 0, true, float><<<1024, thr, 0, stream>>>(
        mlp, Wm2_t + (size_t)l * DF, bm2 + l * NB_D, x, x);
  }

  ln_wave<short><<<NB_M / 4, thr, 0, stream>>>(x, lnf_g, lnf_b, h);
  gemm_bt<2, false, float><<<dim3(1, NB_M / 128), thr, 0, stream>>>(
      h, Wh1t, bh1p, nullptr, hbuf, 128, NB_D);
  head2_kernel<<<NB_M / 8, thr, 0, stream>>>(hbuf, Wh2, bh2, (float*)d_out);
}

// Round 10
// 2844.360 us; speedup vs baseline: 1.1846x; 1.1846x over previous
//
#include <hip/hip_runtime.h>
#include <cstdint>
#include <math.h>

#define NB_B   16
#define NB_T   511
#define NB_S   512
#define NB_OBS 60
#define NB_D   1024
#define NB_H   16
#define NB_L   8
#define NB_DFF 4096
#define NB_HID 100
#define NB_OUT 30
#define NB_M   8192   // B*S rows
#define QKV_S  3072   // merged qkv row stride

typedef __attribute__((ext_vector_type(8))) short  short8;
typedef __attribute__((ext_vector_type(4))) short  short4v;
typedef __attribute__((ext_vector_type(4))) float  f32x4;
typedef __attribute__((ext_vector_type(8))) __bf16 bf16x8;

template <int N_> struct ic { static constexpr int v = N_; };

__device__ __forceinline__ short f2bf(float f) {
  union { float f; unsigned u; } a; a.f = f;
  unsigned u = a.u + 0x7fffu + ((a.u >> 16) & 1u);   // RTNE
  return (short)(u >> 16);
}

__device__ __forceinline__ void load_lds16(const void* g, void* l) {
  __builtin_amdgcn_global_load_lds(
      (__attribute__((address_space(1))) unsigned int*)(uintptr_t)g,
      (__attribute__((address_space(3))) unsigned int*)(unsigned)(uintptr_t)l,
      16, 0, 0);
}

__device__ __forceinline__ f32x4 mfma16(short8 a, short8 b, f32x4 c) {
  return __builtin_amdgcn_mfma_f32_16x16x32_bf16(
      __builtin_bit_cast(bf16x8, a), __builtin_bit_cast(bf16x8, b), c, 0, 0, 0);
}

// gelu via sigmoid form of tanh approx; |err vs exact| <= ~3e-4
__device__ __forceinline__ float gelu_fast(float v) {
  const float t = 1.5957691216057308f * (v + 0.044715f * v * v * v);
  const float e = __expf(fminf(t, 30.f));
  return v * (e / (e + 1.f));
}

// ---------------------------------------------------------------------------
// Weight transpose + fp32->bf16: src (R,C) fp32 -> dst (C,R) bf16 bits
// ---------------------------------------------------------------------------
__global__ __launch_bounds__(256) void tconv2_kernel(
    const float* __restrict__ src, short* __restrict__ dst,
    int R, int C, size_t sstride, size_t dstride) {
  __shared__ float t[64][65];
  const float* s0 = src + blockIdx.z * sstride;
  short* d0 = dst + blockIdx.z * dstride;
  const int c0 = blockIdx.x * 64, r0 = blockIdx.y * 64;
#pragma unroll
  for (int i = 0; i < 4; i++) {
    const int idx = threadIdx.x + i * 256;
    const int r = idx >> 4, c4 = (idx & 15) * 4;
    const float4 v = *(const float4*)&s0[(size_t)(r0 + r) * C + c0 + c4];
    t[r][c4 + 0] = v.x; t[r][c4 + 1] = v.y; t[r][c4 + 2] = v.z; t[r][c4 + 3] = v.w;
  }
  __syncthreads();
#pragma unroll
  for (int i = 0; i < 2; i++) {
    const int idx = threadIdx.x + i * 256;
    const int c = idx >> 3, g = (idx & 7) * 8;
    short8 o;
#pragma unroll
    for (int j = 0; j < 8; j++) o[j] = f2bf(t[g + j][c]);
    *(short8*)&d0[(size_t)(c0 + c) * R + r0 + g] = o;
  }
}

// ---------------------------------------------------------------------------
// Head weight prep + concat qkv bias
// ---------------------------------------------------------------------------
__global__ __launch_bounds__(256) void whead_prep(
    const float* __restrict__ Wh1, const float* __restrict__ bh1,
    short* __restrict__ Wh1t, float* __restrict__ bh1p) {
  const int idx = blockIdx.x * 256 + threadIdx.x;
  const int n = idx >> 10, k = idx & 1023;
  Wh1t[idx] = (n < NB_HID) ? f2bf(Wh1[k * NB_HID + n]) : (short)0;
  if (idx < 128) bh1p[idx] = (idx < NB_HID) ? bh1[idx] : 0.f;
}

__global__ __launch_bounds__(256) void qkvbias_prep(
    const float* __restrict__ bq, const float* __restrict__ bk,
    const float* __restrict__ bv, float* __restrict__ outb) {
  const int idx = blockIdx.x * 256 + threadIdx.x;   // 0 .. 8*3072-1
  const int l = idx / QKV_S, r = idx - l * QKV_S;
  const int z = r >> 10, c = r & 1023;
  const float* src = (z == 0) ? bq : ((z == 1) ? bk : bv);
  outb[idx] = src[l * NB_D + c];
}

// ---------------------------------------------------------------------------
// Token + positional embedding, 8 rows/block
// ---------------------------------------------------------------------------
__global__ __launch_bounds__(256) void embed2_kernel(
    const float* __restrict__ states, const float* __restrict__ goals,
    const float* __restrict__ Wtok, const float* __restrict__ btok,
    const float* __restrict__ pos, float* __restrict__ x) {
  const int r0 = blockIdx.x * 8;
  __shared__ float tok[8][NB_OBS];
  for (int idx = threadIdx.x; idx < 8 * NB_OBS; idx += 256) {
    const int r = idx / NB_OBS, o = idx - r * NB_OBS;
    const int row = r0 + r, b = row >> 9, s = row & 511;
    tok[r][o] = (s == 0) ? goals[b * NB_OBS + o]
                         : states[((size_t)b * NB_T + (s - 1)) * NB_OBS + o];
  }
  __syncthreads();
#pragma unroll
  for (int i = 0; i < 4; i++) {
    const int d = threadIdx.x + i * 256;
    float acc[8];
#pragma unroll
    for (int r = 0; r < 8; r++) acc[r] = 0.f;
    for (int o = 0; o < NB_OBS; o++) {
      const float wv = Wtok[o * NB_D + d];
#pragma unroll
      for (int r = 0; r < 8; r++) acc[r] += tok[r][o] * wv;
    }
    const float bt = btok[d];
#pragma unroll
    for (int r = 0; r < 8; r++) {
      const int row = r0 + r, s = row & 511;
      x[(size_t)row * NB_D + d] = acc[r] + bt + pos[(size_t)s * NB_D + d];
    }
  }
}

// ---------------------------------------------------------------------------
// Wave-per-row LayerNorm: 4 rows/block, no LDS, no barriers.
// ---------------------------------------------------------------------------
template <typename OutT>
__global__ __launch_bounds__(256) void ln_wave(
    const float* __restrict__ xin, const float* __restrict__ gam,
    const float* __restrict__ bet, OutT* __restrict__ outp) {
  const int row = blockIdx.x * 4 + (threadIdx.x >> 6);
  const int lane = threadIdx.x & 63;
  const float4* src = (const float4*)(xin + (size_t)row * NB_D);
  float4 v[4];
  float s = 0.f, s2 = 0.f;
#pragma unroll
  for (int i = 0; i < 4; i++) {
    v[i] = src[lane + 64 * i];
    s += v[i].x + v[i].y + v[i].z + v[i].w;
    s2 += v[i].x * v[i].x + v[i].y * v[i].y + v[i].z * v[i].z + v[i].w * v[i].w;
  }
#pragma unroll
  for (int o = 32; o; o >>= 1) {
    s += __shfl_xor(s, o, 64);
    s2 += __shfl_xor(s2, o, 64);
  }
  const float mean = s * (1.f / NB_D);
  const float var = s2 * (1.f / NB_D) - mean * mean;
  const float rs = rsqrtf(var + 1e-5f);
#pragma unroll
  for (int i = 0; i < 4; i++) {
    const float4 g4 = ((const float4*)gam)[lane + 64 * i];
    const float4 b4 = ((const float4*)bet)[lane + 64 * i];
    const float o0 = (v[i].x - mean) * rs * g4.x + b4.x;
    const float o1 = (v[i].y - mean) * rs * g4.y + b4.y;
    const float o2 = (v[i].z - mean) * rs * g4.z + b4.z;
    const float o3 = (v[i].w - mean) * rs * g4.w + b4.w;
    if constexpr (sizeof(OutT) == 2) {
      short4v r = {f2bf(o0), f2bf(o1), f2bf(o2), f2bf(o3)};
      *(short4v*)((short*)outp + (size_t)row * NB_D + (lane + 64 * i) * 4) = r;
    } else {
      ((float4*)((float*)outp + (size_t)row * NB_D))[lane + 64 * i] =
          make_float4(o0, o1, o2, o3);
    }
  }
}

// ---------------------------------------------------------------------------
// GEMM v4 (round-5 measured-best): BM templated (256 or 128), BN=128, BK=32,
// 256 threads (4 waves 2Mx2N). 3 rotating LDS buffers, depth-2 prefetch,
// counted vmcnt(L), single barrier per K-tile, setprio around MFMA cluster.
// XOR 16B-slot swizzle (pre-swizzled global src, rule #21). Bijective XCD
// chunking, bm-outer/bn-inner.
// ---------------------------------------------------------------------------
template <int BM, int N, int K, int ACT, bool RESID, typename OutT>
__device__ __forceinline__ void gemmv4_core(
    const short* __restrict__ A, const short* __restrict__ Bt,
    const float* __restrict__ bias, const float* __restrict__ resid,
    OutT* __restrict__ C) {
  constexpr int MI = BM / 32;
  constexpr int NK = K / 32;
  constexpr int NBN = N / 128;
  constexpr int NWG = (NB_M / BM) * NBN;
  constexpr int QC = NWG / 8;
  constexpr int L = 2 + BM / 64;
  constexpr int SA = BM * 32;

  __shared__ short As[3][SA];
  __shared__ short Bs[3][128 * 32];

  int wg = blockIdx.x;
  wg = (wg & 7) * QC + (wg >> 3);
  const int bm = (wg / NBN) * BM;
  const int bn = (wg % NBN) * 128;

  const int tid = threadIdx.x;
  const int w = tid >> 6, lane = tid & 63;
  const int wm = w >> 1, wn = w & 1;
  const int rr = lane & 15, sg = lane >> 4;
  const int lrow = lane >> 2, lslot = lane & 3;
  const int sslot = lslot ^ ((lrow >> 1) & 3);

  const short* Asrc = A + (size_t)(bm + w * 16 + lrow) * K + sslot * 8;
  const short* Bsrc = Bt + (size_t)(bn + w * 16 + lrow) * K + sslot * 8;
  short* Adst = &As[0][w * 512];
  short* Bdst = &Bs[0][w * 512];

  const int ar = wm * (BM / 2) + rr;
  const int br = wn * 64 + rr;
  const int aoff = ar * 32 + ((sg ^ ((ar >> 1) & 3)) * 8);
  const int boff = br * 32 + ((sg ^ ((br >> 1) & 3)) * 8);

  f32x4 acc[MI][4];
#pragma unroll
  for (int i = 0; i < MI; i++)
#pragma unroll
    for (int j = 0; j < 4; j++) acc[i][j] = f32x4{0.f, 0.f, 0.f, 0.f};

  auto stage = [&](int sb, int k0) {
    load_lds16(Bsrc + k0,                  Bdst + sb * 4096);
    load_lds16(Bsrc + (size_t)64 * K + k0, Bdst + sb * 4096 + 2048);
#pragma unroll
    for (int c = 0; c < BM / 64; c++)
      load_lds16(Asrc + (size_t)(c * 64) * K + k0, Adst + sb * SA + c * 2048);
  };

  auto gate = [&]() {
    if constexpr (L == 6) asm volatile("s_waitcnt vmcnt(6)" ::: "memory");
    else                  asm volatile("s_waitcnt vmcnt(4)" ::: "memory");
  };

  stage(0, 0);
  stage(1, 32);
  gate();
  __builtin_amdgcn_s_barrier();

  auto ktile = [&](auto BUFC, auto SBUFC, int t) {
    constexpr int BUF = decltype(BUFC)::v;
    constexpr int SBUF = decltype(SBUFC)::v;
    const short* Ab = &As[BUF][0];
    const short* Bb = &Bs[BUF][0];
    if (t + 2 < NK) stage(SBUF, (t + 2) * 32);
    short8 a[MI], b[4];
#pragma unroll
    for (int i = 0; i < MI; i++) a[i] = *(const short8*)(Ab + aoff + i * 512);
#pragma unroll
    for (int j = 0; j < 4; j++) b[j] = *(const short8*)(Bb + boff + j * 512);
    __builtin_amdgcn_s_setprio(1);
#pragma unroll
    for (int i = 0; i < MI; i++)
#pragma unroll
      for (int j = 0; j < 4; j++) acc[i][j] = mfma16(a[i], b[j], acc[i][j]);
    __builtin_amdgcn_s_setprio(0);
    if (t + 2 < NK)      gate();
    else if (t + 1 < NK) asm volatile("s_waitcnt vmcnt(0)" ::: "memory");
    __builtin_amdgcn_s_barrier();
  };

  int t = 0;
#pragma unroll 1
  for (; t + 3 <= NK; t += 3) {
    ktile(ic<0>{}, ic<2>{}, t);
    ktile(ic<1>{}, ic<0>{}, t + 1);
    ktile(ic<2>{}, ic<1>{}, t + 2);
  }
  if constexpr (NK % 3 >= 1) ktile(ic<0>{}, ic<2>{}, NK - NK % 3);
  if constexpr (NK % 3 >= 2) ktile(ic<1>{}, ic<0>{}, NK - NK % 3 + 1);

  const int col0 = bn + wn * 64 + rr;
  float bv[4];
#pragma unroll
  for (int j = 0; j < 4; j++) bv[j] = bias[col0 + j * 16];
#pragma unroll
  for (int i = 0; i < MI; i++) {
#pragma unroll
    for (int q = 0; q < 4; q++) {
      const size_t row = bm + wm * (BM / 2) + i * 16 + sg * 4 + q;
      float v0 = acc[i][0][q] + bv[0];
      float v1 = acc[i][1][q] + bv[1];
      float v2 = acc[i][2][q] + bv[2];
      float v3 = acc[i][3][q] + bv[3];
      if constexpr (RESID) {
        const float* rrow = resid + row * N + col0;
        v0 += rrow[0]; v1 += rrow[16]; v2 += rrow[32]; v3 += rrow[48];
      }
      if constexpr (ACT == 1) {
        v0 = gelu_fast(v0); v1 = gelu_fast(v1);
        v2 = gelu_fast(v2); v3 = gelu_fast(v3);
      }
      OutT* crow = C + row * N + col0;
      if constexpr (sizeof(OutT) == 2) {
        crow[0] = (OutT)f2bf(v0); crow[16] = (OutT)f2bf(v1);
        crow[32] = (OutT)f2bf(v2); crow[48] = (OutT)f2bf(v3);
      } else {
        crow[0] = v0; crow[16] = v1; crow[32] = v2; crow[48] = v3;
      }
    }
  }
}

template <int BM, int N, int K, int ACT, bool RESID, typename OutT>
__global__ __launch_bounds__(256, 2) void gemmv4(
    const short* __restrict__ A, const short* __restrict__ Bt,
    const float* __restrict__ bias, const float* __restrict__ resid,
    OutT* __restrict__ C) {
  gemmv4_core<BM, N, K, ACT, RESID, OutT>(A, Bt, bias, resid, C);
}

// ---------------------------------------------------------------------------
// Head GEMM (N=128): m97 structure, runtime N/K (tiny, one shape).
// ---------------------------------------------------------------------------
template <int ACT, bool RESID, typename OutT>
__global__ __launch_bounds__(256) void gemm_bt(
    const short* __restrict__ A, const short* __restrict__ Bt,
    const float* __restrict__ bias, const float* __restrict__ resid,
    OutT* __restrict__ C, int N, int K) {
  __shared__ short As[128][32];
  __shared__ short Bs[128][32];
  const int bm = blockIdx.y * 128, bn = blockIdx.x * 128;
  const int tid = threadIdx.x;
  const int w = tid >> 6, lane = tid & 63;
  const int wr = (w >> 1) * 64, wc = (w & 1) * 64;
  const int rr = lane & 15, sg = lane >> 4;

  f32x4 acc[4][4];
#pragma unroll
  for (int i = 0; i < 4; i++)
#pragma unroll
    for (int j = 0; j < 4; j++) acc[i][j] = f32x4{0.f, 0.f, 0.f, 0.f};

  const int srow0 = w * 32 + (lane >> 2);
  const int sslot = lane & 3;

  for (int k0 = 0; k0 < K; k0 += 32) {
    __syncthreads();
#pragma unroll
    for (int inst = 0; inst < 2; inst++) {
      const int r = srow0 + inst * 16;
      const int sl = sslot ^ ((r >> 1) & 3);
      load_lds16(A + (size_t)(bm + r) * K + k0 + sl * 8, &As[w * 32 + inst * 16][0]);
      load_lds16(Bt + (size_t)(bn + r) * K + k0 + sl * 8, &Bs[w * 32 + inst * 16][0]);
    }
    __syncthreads();
    short8 a[4], b[4];
#pragma unroll
    for (int i = 0; i < 4; i++) {
      const int r = wr + i * 16 + rr;
      a[i] = *(const short8*)&As[r][(sg ^ ((r >> 1) & 3)) * 8];
      const int c = wc + i * 16 + rr;
      b[i] = *(const short8*)&Bs[c][(sg ^ ((c >> 1) & 3)) * 8];
    }
#pragma unroll
    for (int i = 0; i < 4; i++)
#pragma unroll
      for (int j = 0; j < 4; j++) acc[i][j] = mfma16(a[i], b[j], acc[i][j]);
  }

#pragma unroll
  for (int j = 0; j < 4; j++) {
    const int col = bn + wc + j * 16 + rr;
    const float bv = bias[col];
#pragma unroll
    for (int i = 0; i < 4; i++) {
#pragma unroll
      for (int q = 0; q < 4; q++) {
        const int row = bm + wr + i * 16 + sg * 4 + q;
        float v = acc[i][j][q] + bv;
        if constexpr (RESID) v += resid[(size_t)row * N + col];
        if constexpr (ACT == 1) v = gelu_fast(v);
        if constexpr (ACT == 2) v = v / (1.f + __expf(-v));
        if constexpr (sizeof(OutT) == 2) C[(size_t)row * N + col] = (OutT)f2bf(v);
        else C[(size_t)row * N + col] = v;
      }
    }
  }
}

// ---------------------------------------------------------------------------
// Fused causal flash attention, QBLK=128: block = (qt[0..3], h, b), 4 waves,
// each wave owns 32 q rows (2 groups of 16). K/V staged once per 64-col KV
// tile and reused by 128 q rows (vs 64 before): 1.8x fewer stagings/barriers.
// Fully-masked groups on the diagonal tile are skipped (wave-uniform branch).
// Ps reuse across groups relies on intra-wave LDS program-order (same wave,
// same addresses; compiler inserts lgkmcnt waits).
// ---------------------------------------------------------------------------
__global__ __launch_bounds__(256) void attn2_kernel(
    const short* __restrict__ qkv, short* __restrict__ out) {
  const int qt = blockIdx.x, hh = blockIdx.y, bb = blockIdx.z;
  const int tid = threadIdx.x;
  const int w = tid >> 6, lane = tid & 63;
  const int rr = lane & 15, sg = lane >> 4;

  __shared__ short Ks[64][64];
  __shared__ short Vt[64][64];
  __shared__ short Ps[4][16][64];

  const int qrow_base = qt * 128 + w * 32;   // + g*16

  short8 qf[2][2];
#pragma unroll
  for (int g = 0; g < 2; g++) {
    const size_t qrow = (size_t)bb * NB_S + qrow_base + g * 16 + rr;
#pragma unroll
    for (int ks = 0; ks < 2; ks++)
      qf[g][ks] = *(const short8*)&qkv[qrow * QKV_S + hh * 64 + ks * 32 + sg * 8];
  }

  float mrow[2][4], lrow[2][4];
  f32x4 o[2][4];
#pragma unroll
  for (int g = 0; g < 2; g++)
#pragma unroll
    for (int j = 0; j < 4; j++) {
      mrow[g][j] = -INFINITY; lrow[g][j] = 0.f;
      o[g][j] = f32x4{0.f, 0.f, 0.f, 0.f};
    }

  const int ktmax = 2 * qt + 1;
  for (int kt = 0; kt <= ktmax; kt++) {
    __syncthreads();
    {  // stage K tile (offset 1024 within merged row)
      const int p = lane & 7;
#pragma unroll
      for (int inst = 0; inst < 2; inst++) {
        const int r = w * 16 + inst * 8 + (lane >> 3);
        const int sl = p ^ (r & 7);
        load_lds16(qkv + ((size_t)bb * NB_S + kt * 64 + r) * QKV_S + 1024 + hh * 64 + sl * 8,
                   &Ks[w * 16 + inst * 8][0]);
      }
    }
    {  // stage V transposed (offset 2048)
#pragma unroll
      for (int cc = 0; cc < 2; cc++) {
        const int c = tid * 2 + cc;
        const int sk = c >> 3, sl = c & 7;
        short8 vv = *(const short8*)&qkv[((size_t)bb * NB_S + kt * 64 + sk) * QKV_S + 2048 + hh * 64 + sl * 8];
        const int ss = sk >> 3;
#pragma unroll
        for (int j = 0; j < 8; j++) {
          const int dh = sl * 8 + j;
          Vt[dh][(ss ^ (dh & 7)) * 8 + (sk & 7)] = vv[j];
        }
      }
    }
    __syncthreads();

#pragma unroll
    for (int g = 0; g < 2; g++) {
      if (kt * 64 > qrow_base + g * 16 + 15) continue;   // fully masked

      f32x4 sf[4];
#pragma unroll
      for (int nb = 0; nb < 4; nb++) sf[nb] = f32x4{0.f, 0.f, 0.f, 0.f};
#pragma unroll
      for (int ks = 0; ks < 2; ks++) {
#pragma unroll
        for (int nb = 0; nb < 4; nb++) {
          const int ck = nb * 16 + rr;
          short8 kf = *(const short8*)&Ks[ck][((ks * 4 + sg) ^ (ck & 7)) * 8];
          sf[nb] = mfma16(qf[g][ks], kf, sf[nb]);
        }
      }
      const int rbase = qrow_base + g * 16 + sg * 4;
      float pmax[4] = {-INFINITY, -INFINITY, -INFINITY, -INFINITY};
#pragma unroll
      for (int nb = 0; nb < 4; nb++) {
        const int cg = kt * 64 + nb * 16 + rr;
#pragma unroll
        for (int j = 0; j < 4; j++) {
          float sv = sf[nb][j] * 0.125f;
          if (cg > rbase + j) sv = -INFINITY;
          sf[nb][j] = sv;
          pmax[j] = fmaxf(pmax[j], sv);
        }
      }
#pragma unroll
      for (int o1 = 1; o1 < 16; o1 <<= 1)
#pragma unroll
        for (int j = 0; j < 4; j++)
          pmax[j] = fmaxf(pmax[j], __shfl_xor(pmax[j], o1, 64));

      float resc[4], psum[4];
#pragma unroll
      for (int j = 0; j < 4; j++) {
        const float mn = fmaxf(mrow[g][j], pmax[j]);
        resc[j] = __expf(mrow[g][j] - mn);
        mrow[g][j] = mn;
        psum[j] = 0.f;
      }
#pragma unroll
      for (int nb = 0; nb < 4; nb++)
#pragma unroll
        for (int j = 0; j < 4; j++) {
          const float p = __expf(sf[nb][j] - mrow[g][j]);
          sf[nb][j] = p;
          psum[j] += p;
        }
#pragma unroll
      for (int o1 = 1; o1 < 16; o1 <<= 1)
#pragma unroll
        for (int j = 0; j < 4; j++) psum[j] += __shfl_xor(psum[j], o1, 64);
#pragma unroll
      for (int j = 0; j < 4; j++) lrow[g][j] = lrow[g][j] * resc[j] + psum[j];
#pragma unroll
      for (int nb = 0; nb < 4; nb++)
#pragma unroll
        for (int j = 0; j < 4; j++) o[g][nb][j] *= resc[j];

#pragma unroll
      for (int nb = 0; nb < 4; nb++) {
        const int ck = nb * 16 + rr;
        const int ss = ck >> 3;
#pragma unroll
        for (int j = 0; j < 4; j++) {
          const int rq = sg * 4 + j;
          Ps[w][rq][(ss ^ (rq & 7)) * 8 + (ck & 7)] = f2bf(sf[nb][j]);
        }
      }
#pragma unroll
      for (int ks = 0; ks < 2; ks++) {
        short8 pf = *(const short8*)&Ps[w][rr][((ks * 4 + sg) ^ (rr & 7)) * 8];
#pragma unroll
        for (int nb = 0; nb < 4; nb++) {
          const int dh = nb * 16 + rr;
          short8 vf = *(const short8*)&Vt[dh][((ks * 4 + sg) ^ (dh & 7)) * 8];
          o[g][nb] = mfma16(pf, vf, o[g][nb]);
        }
      }
    }
  }

#pragma unroll
  for (int g = 0; g < 2; g++) {
    const size_t orow0 = (size_t)bb * NB_S + qrow_base + g * 16;
#pragma unroll
    for (int nb = 0; nb < 4; nb++)
#pragma unroll
      for (int j = 0; j < 4; j++) {
        const float v = o[g][nb][j] / lrow[g][j];
        out[(orow0 + sg * 4 + j) * NB_D + hh * 64 + nb * 16 + rr] = f2bf(v);
      }
  }
}

// ---------------------------------------------------------------------------
// Head stage 2: out(8176,30) = hbuf(.,100) @ Wh2(100,30) + bh2, fp32.
// ---------------------------------------------------------------------------
__global__ __launch_bounds__(256) void head2_kernel(
    const float* __restrict__ hbuf, const float* __restrict__ Wh2,
    const float* __restrict__ bh2, float* __restrict__ outp) {
  __shared__ float hs[8][NB_HID];
  const int g0 = blockIdx.x * 8;
  for (int idx = threadIdx.x; idx < 8 * NB_HID; idx += 256) {
    const int r = idx / NB_HID, k = idx - r * NB_HID;
    const int gt = g0 + r;
    const int b = gt / NB_T, tt = gt - b * NB_T;
    hs[r][k] = hbuf[(size_t)(b * NB_S + 1 + tt) * 128 + k];
  }
  __syncthreads();
  const int r = threadIdx.x >> 5, c = threadIdx.x & 31;
  if (c < NB_OUT) {
    float acc = bh2[c];
#pragma unroll
    for (int k = 0; k < NB_HID; k++) acc += hs[r][k] * Wh2[k * NB_OUT + c];
    outp[(size_t)(g0 + r) * NB_OUT + c] = acc;
  }
}

// ---------------------------------------------------------------------------
extern "C" void kernel_launch(void* const* d_in, const int* in_sizes, int n_in,
                              void* d_out, int out_size, void* d_ws, size_t ws_size,
                              hipStream_t stream) {
  const float* states = (const float*)d_in[0];
  const float* goals  = (const float*)d_in[1];
  const float* Wtok   = (const float*)d_in[2];
  const float* btok   = (const float*)d_in[3];
  const float* pos    = (const float*)d_in[4];
  const float* ln1_g  = (const float*)d_in[5];
  const float* ln1_b  = (const float*)d_in[6];
  const float* Wq     = (const float*)d_in[7];
  const float* bq     = (const float*)d_in[8];
  const float* Wk     = (const float*)d_in[9];
  const float* bk     = (const float*)d_in[10];
  const float* Wv     = (const float*)d_in[11];
  const float* bv     = (const float*)d_in[12];
  const float* Wp     = (const float*)d_in[13];
  const float* bp     = (const float*)d_in[14];
  const float* ln2_g  = (const float*)d_in[15];
  const float* ln2_b  = (const float*)d_in[16];
  const float* Wm1    = (const float*)d_in[17];
  const float* bm1    = (const float*)d_in[18];
  const float* Wm2    = (const float*)d_in[19];
  const float* bm2    = (const float*)d_in[20];
  const float* lnf_g  = (const float*)d_in[21];
  const float* lnf_b  = (const float*)d_in[22];
  const float* Wh1    = (const float*)d_in[23];
  const float* bh1    = (const float*)d_in[24];
  const float* Wh2    = (const float*)d_in[25];
  const float* bh2    = (const float*)d_in[26];

  char* wsp = (char*)d_ws;
  size_t off = 0;
  auto carve = [&](size_t bytes) -> char* {
    char* p = wsp + off;
    off += (bytes + 1023) & ~(size_t)1023;
    return p;
  };
  short* Wqkv_t = (short*)carve((size_t)NB_L * 3 * NB_D * NB_D * 2);  // (l, 3072, 1024)
  short* Wp_t   = (short*)carve((size_t)NB_L * NB_D * NB_D * 2);
  short* Wm1_t  = (short*)carve((size_t)NB_L * NB_DFF * NB_D * 2);
  short* Wm2_t  = (short*)carve((size_t)NB_L * NB_D * NB_DFF * 2);
  float* x      = (float*)carve((size_t)NB_M * NB_D * 4);
  short* h      = (short*)carve((size_t)NB_M * NB_D * 2);
  short* qkvb   = (short*)carve((size_t)NB_M * QKV_S * 2);
  short* mlp    = (short*)carve((size_t)NB_M * NB_DFF * 2);
  short* Wh1t   = (short*)carve((size_t)128 * NB_D * 2);
  float* bh1p   = (float*)carve(128 * 4);
  float* bqkv   = (float*)carve((size_t)NB_L * QKV_S * 4);
  short* attout = mlp;           // alias: dead before mlp is written
  float* hbuf   = (float*)qkvb;  // alias: qkv dead after last attention

  const dim3 thr(256);
  const size_t DD = (size_t)NB_D * NB_D;
  const size_t DF = (size_t)NB_D * NB_DFF;

  tconv2_kernel<<<dim3(16, 16, NB_L), thr, 0, stream>>>(Wq, Wqkv_t + 0 * DD, NB_D, NB_D, DD, 3 * DD);
  tconv2_kernel<<<dim3(16, 16, NB_L), thr, 0, stream>>>(Wk, Wqkv_t + 1 * DD, NB_D, NB_D, DD, 3 * DD);
  tconv2_kernel<<<dim3(16, 16, NB_L), thr, 0, stream>>>(Wv, Wqkv_t + 2 * DD, NB_D, NB_D, DD, 3 * DD);
  tconv2_kernel<<<dim3(16, 16, NB_L), thr, 0, stream>>>(Wp, Wp_t, NB_D, NB_D, DD, DD);
  tconv2_kernel<<<dim3(64, 16, NB_L), thr, 0, stream>>>(Wm1, Wm1_t, NB_D, NB_DFF, DF, DF);
  tconv2_kernel<<<dim3(16, 64, NB_L), thr, 0, stream>>>(Wm2, Wm2_t, NB_DFF, NB_D, DF, DF);
  whead_prep<<<512, thr, 0, stream>>>(Wh1, bh1, Wh1t, bh1p);
  qkvbias_prep<<<96, thr, 0, stream>>>(bq, bk, bv, bqkv);

  embed2_kernel<<<NB_M / 8, thr, 0, stream>>>(states, goals, Wtok, btok, pos, x);

  for (int l = 0; l < NB_L; l++) {
    ln_wave<short><<<NB_M / 4, thr, 0, stream>>>(x, ln1_g + l * NB_D, ln1_b + l * NB_D, h);
    gemmv4<256, QKV_S, NB_D, 0, false, short><<<768, thr, 0, stream>>>(
        h, Wqkv_t + (size_t)l * 3 * DD, bqkv + (size_t)l * QKV_S, nullptr, qkvb);
    attn2_kernel<<<dim3(NB_S / 128, NB_H, NB_B), thr, 0, stream>>>(qkvb, attout);
    gemmv4<128, NB_D, NB_D, 0, true, float><<<512, thr, 0, stream>>>(
        attout, Wp_t + (size_t)l * DD, bp + l * NB_D, x, x);
    ln_wave<short><<<NB_M / 4, thr, 0, stream>>>(x, ln2_g + l * NB_D, ln2_b + l * NB_D, h);
    gemmv4<256, NB_DFF, NB_D, 1, false, short><<<1024, thr, 0, stream>>>(
        h, Wm1_t + (size_t)l * DF, bm1 + l * NB_DFF, nullptr, mlp);
    gemmv4<128, NB_D, NB_DFF, 0, true, float><<<512, thr, 0, stream>>>(
        mlp, Wm2_t + (size_t)l * DF, bm2 + l * NB_D, x, x);
  }

  ln_wave<short><<<NB_M / 4, thr, 0, stream>>>(x, lnf_g, lnf_b, h);
  gemm_bt<2, false, float><<<dim3(1, NB_M / 128), thr, 0, stream>>>(
      h, Wh1t, bh1p, nullptr, hbuf, 128, NB_D);
  head2_kernel<<<NB_M / 8, thr, 0, stream>>>(hbuf, Wh2, bh2, (float*)d_out);
}

// Round 11
// 2811.148 us; speedup vs baseline: 1.1986x; 1.0118x over previous
//
#include <hip/hip_runtime.h>
#include <cstdint>
#include <math.h>

#define NB_B   16
#define NB_T   511
#define NB_S   512
#define NB_OBS 60
#define NB_D   1024
#define NB_H   16
#define NB_L   8
#define NB_DFF 4096
#define NB_HID 100
#define NB_OUT 30
#define NB_M   8192   // B*S rows
#define QKV_S  3072   // merged qkv row stride

typedef __attribute__((ext_vector_type(8))) short  short8;
typedef __attribute__((ext_vector_type(4))) short  short4v;
typedef __attribute__((ext_vector_type(4))) float  f32x4;
typedef __attribute__((ext_vector_type(8))) __bf16 bf16x8;

template <int N_> struct ic { static constexpr int v = N_; };

__device__ __forceinline__ short f2bf(float f) {
  union { float f; unsigned u; } a; a.f = f;
  unsigned u = a.u + 0x7fffu + ((a.u >> 16) & 1u);   // RTNE
  return (short)(u >> 16);
}

__device__ __forceinline__ void load_lds16(const void* g, void* l) {
  __builtin_amdgcn_global_load_lds(
      (__attribute__((address_space(1))) unsigned int*)(uintptr_t)g,
      (__attribute__((address_space(3))) unsigned int*)(unsigned)(uintptr_t)l,
      16, 0, 0);
}

__device__ __forceinline__ f32x4 mfma16(short8 a, short8 b, f32x4 c) {
  return __builtin_amdgcn_mfma_f32_16x16x32_bf16(
      __builtin_bit_cast(bf16x8, a), __builtin_bit_cast(bf16x8, b), c, 0, 0, 0);
}

// gelu via sigmoid form of tanh approx; |err vs exact| <= ~3e-4
__device__ __forceinline__ float gelu_fast(float v) {
  const float t = 1.5957691216057308f * (v + 0.044715f * v * v * v);
  const float e = __expf(fminf(t, 30.f));
  return v * (e / (e + 1.f));
}

// ---------------------------------------------------------------------------
// Weight transpose + fp32->bf16: src (R,C) fp32 -> dst (C,R) bf16 bits
// ---------------------------------------------------------------------------
__global__ __launch_bounds__(256) void tconv2_kernel(
    const float* __restrict__ src, short* __restrict__ dst,
    int R, int C, size_t sstride, size_t dstride) {
  __shared__ float t[64][65];
  const float* s0 = src + blockIdx.z * sstride;
  short* d0 = dst + blockIdx.z * dstride;
  const int c0 = blockIdx.x * 64, r0 = blockIdx.y * 64;
#pragma unroll
  for (int i = 0; i < 4; i++) {
    const int idx = threadIdx.x + i * 256;
    const int r = idx >> 4, c4 = (idx & 15) * 4;
    const float4 v = *(const float4*)&s0[(size_t)(r0 + r) * C + c0 + c4];
    t[r][c4 + 0] = v.x; t[r][c4 + 1] = v.y; t[r][c4 + 2] = v.z; t[r][c4 + 3] = v.w;
  }
  __syncthreads();
#pragma unroll
  for (int i = 0; i < 2; i++) {
    const int idx = threadIdx.x + i * 256;
    const int c = idx >> 3, g = (idx & 7) * 8;
    short8 o;
#pragma unroll
    for (int j = 0; j < 8; j++) o[j] = f2bf(t[g + j][c]);
    *(short8*)&d0[(size_t)(c0 + c) * R + r0 + g] = o;
  }
}

// ---------------------------------------------------------------------------
// Head weight prep + concat qkv bias
// ---------------------------------------------------------------------------
__global__ __launch_bounds__(256) void whead_prep(
    const float* __restrict__ Wh1, const float* __restrict__ bh1,
    short* __restrict__ Wh1t, float* __restrict__ bh1p) {
  const int idx = blockIdx.x * 256 + threadIdx.x;
  const int n = idx >> 10, k = idx & 1023;
  Wh1t[idx] = (n < NB_HID) ? f2bf(Wh1[k * NB_HID + n]) : (short)0;
  if (idx < 128) bh1p[idx] = (idx < NB_HID) ? bh1[idx] : 0.f;
}

__global__ __launch_bounds__(256) void qkvbias_prep(
    const float* __restrict__ bq, const float* __restrict__ bk,
    const float* __restrict__ bv, float* __restrict__ outb) {
  const int idx = blockIdx.x * 256 + threadIdx.x;   // 0 .. 8*3072-1
  const int l = idx / QKV_S, r = idx - l * QKV_S;
  const int z = r >> 10, c = r & 1023;
  const float* src = (z == 0) ? bq : ((z == 1) ? bk : bv);
  outb[idx] = src[l * NB_D + c];
}

// ---------------------------------------------------------------------------
// Token + positional embedding, 8 rows/block
// ---------------------------------------------------------------------------
__global__ __launch_bounds__(256) void embed2_kernel(
    const float* __restrict__ states, const float* __restrict__ goals,
    const float* __restrict__ Wtok, const float* __restrict__ btok,
    const float* __restrict__ pos, float* __restrict__ x) {
  const int r0 = blockIdx.x * 8;
  __shared__ float tok[8][NB_OBS];
  for (int idx = threadIdx.x; idx < 8 * NB_OBS; idx += 256) {
    const int r = idx / NB_OBS, o = idx - r * NB_OBS;
    const int row = r0 + r, b = row >> 9, s = row & 511;
    tok[r][o] = (s == 0) ? goals[b * NB_OBS + o]
                         : states[((size_t)b * NB_T + (s - 1)) * NB_OBS + o];
  }
  __syncthreads();
#pragma unroll
  for (int i = 0; i < 4; i++) {
    const int d = threadIdx.x + i * 256;
    float acc[8];
#pragma unroll
    for (int r = 0; r < 8; r++) acc[r] = 0.f;
    for (int o = 0; o < NB_OBS; o++) {
      const float wv = Wtok[o * NB_D + d];
#pragma unroll
      for (int r = 0; r < 8; r++) acc[r] += tok[r][o] * wv;
    }
    const float bt = btok[d];
#pragma unroll
    for (int r = 0; r < 8; r++) {
      const int row = r0 + r, s = row & 511;
      x[(size_t)row * NB_D + d] = acc[r] + bt + pos[(size_t)s * NB_D + d];
    }
  }
}

// ---------------------------------------------------------------------------
// Wave-per-row LayerNorm: 4 rows/block, no LDS, no barriers.
// ---------------------------------------------------------------------------
template <typename OutT>
__global__ __launch_bounds__(256) void ln_wave(
    const float* __restrict__ xin, const float* __restrict__ gam,
    const float* __restrict__ bet, OutT* __restrict__ outp) {
  const int row = blockIdx.x * 4 + (threadIdx.x >> 6);
  const int lane = threadIdx.x & 63;
  const float4* src = (const float4*)(xin + (size_t)row * NB_D);
  float4 v[4];
  float s = 0.f, s2 = 0.f;
#pragma unroll
  for (int i = 0; i < 4; i++) {
    v[i] = src[lane + 64 * i];
    s += v[i].x + v[i].y + v[i].z + v[i].w;
    s2 += v[i].x * v[i].x + v[i].y * v[i].y + v[i].z * v[i].z + v[i].w * v[i].w;
  }
#pragma unroll
  for (int o = 32; o; o >>= 1) {
    s += __shfl_xor(s, o, 64);
    s2 += __shfl_xor(s2, o, 64);
  }
  const float mean = s * (1.f / NB_D);
  const float var = s2 * (1.f / NB_D) - mean * mean;
  const float rs = rsqrtf(var + 1e-5f);
#pragma unroll
  for (int i = 0; i < 4; i++) {
    const float4 g4 = ((const float4*)gam)[lane + 64 * i];
    const float4 b4 = ((const float4*)bet)[lane + 64 * i];
    const float o0 = (v[i].x - mean) * rs * g4.x + b4.x;
    const float o1 = (v[i].y - mean) * rs * g4.y + b4.y;
    const float o2 = (v[i].z - mean) * rs * g4.z + b4.z;
    const float o3 = (v[i].w - mean) * rs * g4.w + b4.w;
    if constexpr (sizeof(OutT) == 2) {
      short4v r = {f2bf(o0), f2bf(o1), f2bf(o2), f2bf(o3)};
      *(short4v*)((short*)outp + (size_t)row * NB_D + (lane + 64 * i) * 4) = r;
    } else {
      ((float4*)((float*)outp + (size_t)row * NB_D))[lane + 64 * i] =
          make_float4(o0, o1, o2, o3);
    }
  }
}

// ---------------------------------------------------------------------------
// GEMM v4g: round-5 pipeline (3 rotating LDS buffers, depth-2 prefetch,
// counted vmcnt, 1 barrier/K-tile, setprio) + GROUP_N=8 chunk-local ordering:
// within each XCD chunk, sweep bm against a group of 8 resident B panels
// (8x256KB = 2MB + A 512KB < 4MB L2) so B staging hits L2 (~200cy) instead of
// L3/HBM (~900cy) -- brings miss latency inside the depth-2 prefetch cover.
// ---------------------------------------------------------------------------
template <int BM, int N, int K, int ACT, bool RESID, typename OutT>
__device__ __forceinline__ void gemmv4_core(
    const short* __restrict__ A, const short* __restrict__ Bt,
    const float* __restrict__ bias, const float* __restrict__ resid,
    OutT* __restrict__ C) {
  constexpr int MI = BM / 32;
  constexpr int NK = K / 32;
  constexpr int NBN = N / 128;
  constexpr int NWG = (NB_M / BM) * NBN;
  constexpr int QC = NWG / 8;          // wgs per XCD chunk
  constexpr int CBM = QC / NBN;        // bm-tiles per chunk
  constexpr int GN = (NBN < 8) ? NBN : 8;
  constexpr int L = 2 + BM / 64;
  constexpr int SA = BM * 32;

  __shared__ short As[3][SA];
  __shared__ short Bs[3][128 * 32];

  int wg = blockIdx.x;
  wg = (wg & 7) * QC + (wg >> 3);       // bijective XCD chunking
  const int chunk = wg / QC;
  const int idx = wg - chunk * QC;
  const int grp = idx / (CBM * GN);     // bn-group of GN panels
  const int r2 = idx - grp * (CBM * GN);
  const int bm = (chunk * CBM + r2 / GN) * BM;
  const int bn = (grp * GN + r2 % GN) * 128;

  const int tid = threadIdx.x;
  const int w = tid >> 6, lane = tid & 63;
  const int wm = w >> 1, wn = w & 1;
  const int rr = lane & 15, sg = lane >> 4;
  const int lrow = lane >> 2, lslot = lane & 3;
  const int sslot = lslot ^ ((lrow >> 1) & 3);

  const short* Asrc = A + (size_t)(bm + w * 16 + lrow) * K + sslot * 8;
  const short* Bsrc = Bt + (size_t)(bn + w * 16 + lrow) * K + sslot * 8;
  short* Adst = &As[0][w * 512];
  short* Bdst = &Bs[0][w * 512];

  const int ar = wm * (BM / 2) + rr;
  const int br = wn * 64 + rr;
  const int aoff = ar * 32 + ((sg ^ ((ar >> 1) & 3)) * 8);
  const int boff = br * 32 + ((sg ^ ((br >> 1) & 3)) * 8);

  f32x4 acc[MI][4];
#pragma unroll
  for (int i = 0; i < MI; i++)
#pragma unroll
    for (int j = 0; j < 4; j++) acc[i][j] = f32x4{0.f, 0.f, 0.f, 0.f};

  auto stage = [&](int sb, int k0) {
    load_lds16(Bsrc + k0,                  Bdst + sb * 4096);
    load_lds16(Bsrc + (size_t)64 * K + k0, Bdst + sb * 4096 + 2048);
#pragma unroll
    for (int c = 0; c < BM / 64; c++)
      load_lds16(Asrc + (size_t)(c * 64) * K + k0, Adst + sb * SA + c * 2048);
  };

  auto gate = [&]() {
    if constexpr (L == 6) asm volatile("s_waitcnt vmcnt(6)" ::: "memory");
    else                  asm volatile("s_waitcnt vmcnt(4)" ::: "memory");
  };

  stage(0, 0);
  stage(1, 32);
  gate();
  __builtin_amdgcn_s_barrier();

  auto ktile = [&](auto BUFC, auto SBUFC, int t) {
    constexpr int BUF = decltype(BUFC)::v;
    constexpr int SBUF = decltype(SBUFC)::v;
    const short* Ab = &As[BUF][0];
    const short* Bb = &Bs[BUF][0];
    if (t + 2 < NK) stage(SBUF, (t + 2) * 32);
    short8 a[MI], b[4];
#pragma unroll
    for (int i = 0; i < MI; i++) a[i] = *(const short8*)(Ab + aoff + i * 512);
#pragma unroll
    for (int j = 0; j < 4; j++) b[j] = *(const short8*)(Bb + boff + j * 512);
    __builtin_amdgcn_s_setprio(1);
#pragma unroll
    for (int i = 0; i < MI; i++)
#pragma unroll
      for (int j = 0; j < 4; j++) acc[i][j] = mfma16(a[i], b[j], acc[i][j]);
    __builtin_amdgcn_s_setprio(0);
    if (t + 2 < NK)      gate();
    else if (t + 1 < NK) asm volatile("s_waitcnt vmcnt(0)" ::: "memory");
    __builtin_amdgcn_s_barrier();
  };

  int t = 0;
#pragma unroll 1
  for (; t + 3 <= NK; t += 3) {
    ktile(ic<0>{}, ic<2>{}, t);
    ktile(ic<1>{}, ic<0>{}, t + 1);
    ktile(ic<2>{}, ic<1>{}, t + 2);
  }
  if constexpr (NK % 3 >= 1) ktile(ic<0>{}, ic<2>{}, NK - NK % 3);
  if constexpr (NK % 3 >= 2) ktile(ic<1>{}, ic<0>{}, NK - NK % 3 + 1);

  const int col0 = bn + wn * 64 + rr;
  float bv[4];
#pragma unroll
  for (int j = 0; j < 4; j++) bv[j] = bias[col0 + j * 16];
#pragma unroll
  for (int i = 0; i < MI; i++) {
#pragma unroll
    for (int q = 0; q < 4; q++) {
      const size_t row = bm + wm * (BM / 2) + i * 16 + sg * 4 + q;
      float v0 = acc[i][0][q] + bv[0];
      float v1 = acc[i][1][q] + bv[1];
      float v2 = acc[i][2][q] + bv[2];
      float v3 = acc[i][3][q] + bv[3];
      if constexpr (RESID) {
        const float* rrow = resid + row * N + col0;
        v0 += rrow[0]; v1 += rrow[16]; v2 += rrow[32]; v3 += rrow[48];
      }
      if constexpr (ACT == 1) {
        v0 = gelu_fast(v0); v1 = gelu_fast(v1);
        v2 = gelu_fast(v2); v3 = gelu_fast(v3);
      }
      OutT* crow = C + row * N + col0;
      if constexpr (sizeof(OutT) == 2) {
        crow[0] = (OutT)f2bf(v0); crow[16] = (OutT)f2bf(v1);
        crow[32] = (OutT)f2bf(v2); crow[48] = (OutT)f2bf(v3);
      } else {
        crow[0] = v0; crow[16] = v1; crow[32] = v2; crow[48] = v3;
      }
    }
  }
}

template <int BM, int N, int K, int ACT, bool RESID, typename OutT>
__global__ __launch_bounds__(256, 2) void gemmv4(
    const short* __restrict__ A, const short* __restrict__ Bt,
    const float* __restrict__ bias, const float* __restrict__ resid,
    OutT* __restrict__ C) {
  gemmv4_core<BM, N, K, ACT, RESID, OutT>(A, Bt, bias, resid, C);
}

// ---------------------------------------------------------------------------
// Head GEMM (N=128): m97 structure, runtime N/K (tiny, one shape).
// ---------------------------------------------------------------------------
template <int ACT, bool RESID, typename OutT>
__global__ __launch_bounds__(256) void gemm_bt(
    const short* __restrict__ A, const short* __restrict__ Bt,
    const float* __restrict__ bias, const float* __restrict__ resid,
    OutT* __restrict__ C, int N, int K) {
  __shared__ short As[128][32];
  __shared__ short Bs[128][32];
  const int bm = blockIdx.y * 128, bn = blockIdx.x * 128;
  const int tid = threadIdx.x;
  const int w = tid >> 6, lane = tid & 63;
  const int wr = (w >> 1) * 64, wc = (w & 1) * 64;
  const int rr = lane & 15, sg = lane >> 4;

  f32x4 acc[4][4];
#pragma unroll
  for (int i = 0; i < 4; i++)
#pragma unroll
    for (int j = 0; j < 4; j++) acc[i][j] = f32x4{0.f, 0.f, 0.f, 0.f};

  const int srow0 = w * 32 + (lane >> 2);
  const int sslot = lane & 3;

  for (int k0 = 0; k0 < K; k0 += 32) {
    __syncthreads();
#pragma unroll
    for (int inst = 0; inst < 2; inst++) {
      const int r = srow0 + inst * 16;
      const int sl = sslot ^ ((r >> 1) & 3);
      load_lds16(A + (size_t)(bm + r) * K + k0 + sl * 8, &As[w * 32 + inst * 16][0]);
      load_lds16(Bt + (size_t)(bn + r) * K + k0 + sl * 8, &Bs[w * 32 + inst * 16][0]);
    }
    __syncthreads();
    short8 a[4], b[4];
#pragma unroll
    for (int i = 0; i < 4; i++) {
      const int r = wr + i * 16 + rr;
      a[i] = *(const short8*)&As[r][(sg ^ ((r >> 1) & 3)) * 8];
      const int c = wc + i * 16 + rr;
      b[i] = *(const short8*)&Bs[c][(sg ^ ((c >> 1) & 3)) * 8];
    }
#pragma unroll
    for (int i = 0; i < 4; i++)
#pragma unroll
      for (int j = 0; j < 4; j++) acc[i][j] = mfma16(a[i], b[j], acc[i][j]);
  }

#pragma unroll
  for (int j = 0; j < 4; j++) {
    const int col = bn + wc + j * 16 + rr;
    const float bv = bias[col];
#pragma unroll
    for (int i = 0; i < 4; i++) {
#pragma unroll
      for (int q = 0; q < 4; q++) {
        const int row = bm + wr + i * 16 + sg * 4 + q;
        float v = acc[i][j][q] + bv;
        if constexpr (RESID) v += resid[(size_t)row * N + col];
        if constexpr (ACT == 1) v = gelu_fast(v);
        if constexpr (ACT == 2) v = v / (1.f + __expf(-v));
        if constexpr (sizeof(OutT) == 2) C[(size_t)row * N + col] = (OutT)f2bf(v);
        else C[(size_t)row * N + col] = v;
      }
    }
  }
}

// ---------------------------------------------------------------------------
// Fused causal flash attention, QBLK=128, rowsum-via-MFMA (l = P @ 1 folded
// into the matrix pipe; denominator uses the same bf16-rounded P as PV).
// ---------------------------------------------------------------------------
__global__ __launch_bounds__(256) void attn2_kernel(
    const short* __restrict__ qkv, short* __restrict__ out) {
  const int qt = blockIdx.x, hh = blockIdx.y, bb = blockIdx.z;
  const int tid = threadIdx.x;
  const int w = tid >> 6, lane = tid & 63;
  const int rr = lane & 15, sg = lane >> 4;

  __shared__ short Ks[64][64];
  __shared__ short Vt[64][64];
  __shared__ short Ps[4][16][64];

  const short ONEB = 0x3F80;   // bf16 1.0
  const short8 ones8 = {ONEB, ONEB, ONEB, ONEB, ONEB, ONEB, ONEB, ONEB};

  const int qrow_base = qt * 128 + w * 32;   // + g*16

  short8 qf[2][2];
#pragma unroll
  for (int g = 0; g < 2; g++) {
    const size_t qrow = (size_t)bb * NB_S + qrow_base + g * 16 + rr;
#pragma unroll
    for (int ks = 0; ks < 2; ks++)
      qf[g][ks] = *(const short8*)&qkv[qrow * QKV_S + hh * 64 + ks * 32 + sg * 8];
  }

  float mrow[2][4], lrow[2][4];
  f32x4 o[2][4];
#pragma unroll
  for (int g = 0; g < 2; g++)
#pragma unroll
    for (int j = 0; j < 4; j++) {
      mrow[g][j] = -INFINITY; lrow[g][j] = 0.f;
      o[g][j] = f32x4{0.f, 0.f, 0.f, 0.f};
    }

  const int ktmax = 2 * qt + 1;
  for (int kt = 0; kt <= ktmax; kt++) {
    __syncthreads();
    {  // stage K tile (offset 1024 within merged row)
      const int p = lane & 7;
#pragma unroll
      for (int inst = 0; inst < 2; inst++) {
        const int r = w * 16 + inst * 8 + (lane >> 3);
        const int sl = p ^ (r & 7);
        load_lds16(qkv + ((size_t)bb * NB_S + kt * 64 + r) * QKV_S + 1024 + hh * 64 + sl * 8,
                   &Ks[w * 16 + inst * 8][0]);
      }
    }
    {  // stage V transposed (offset 2048)
#pragma unroll
      for (int cc = 0; cc < 2; cc++) {
        const int c = tid * 2 + cc;
        const int sk = c >> 3, sl = c & 7;
        short8 vv = *(const short8*)&qkv[((size_t)bb * NB_S + kt * 64 + sk) * QKV_S + 2048 + hh * 64 + sl * 8];
        const int ss = sk >> 3;
#pragma unroll
        for (int j = 0; j < 8; j++) {
          const int dh = sl * 8 + j;
          Vt[dh][(ss ^ (dh & 7)) * 8 + (sk & 7)] = vv[j];
        }
      }
    }
    __syncthreads();

#pragma unroll
    for (int g = 0; g < 2; g++) {
      if (kt * 64 > qrow_base + g * 16 + 15) continue;   // fully masked

      f32x4 sf[4];
#pragma unroll
      for (int nb = 0; nb < 4; nb++) sf[nb] = f32x4{0.f, 0.f, 0.f, 0.f};
#pragma unroll
      for (int ks = 0; ks < 2; ks++) {
#pragma unroll
        for (int nb = 0; nb < 4; nb++) {
          const int ck = nb * 16 + rr;
          short8 kf = *(const short8*)&Ks[ck][((ks * 4 + sg) ^ (ck & 7)) * 8];
          sf[nb] = mfma16(qf[g][ks], kf, sf[nb]);
        }
      }
      const int rbase = qrow_base + g * 16 + sg * 4;
      float pmax[4] = {-INFINITY, -INFINITY, -INFINITY, -INFINITY};
#pragma unroll
      for (int nb = 0; nb < 4; nb++) {
        const int cg = kt * 64 + nb * 16 + rr;
#pragma unroll
        for (int j = 0; j < 4; j++) {
          float sv = sf[nb][j] * 0.125f;
          if (cg > rbase + j) sv = -INFINITY;
          sf[nb][j] = sv;
          pmax[j] = fmaxf(pmax[j], sv);
        }
      }
#pragma unroll
      for (int o1 = 1; o1 < 16; o1 <<= 1)
#pragma unroll
        for (int j = 0; j < 4; j++)
          pmax[j] = fmaxf(pmax[j], __shfl_xor(pmax[j], o1, 64));

      float resc[4];
#pragma unroll
      for (int j = 0; j < 4; j++) {
        const float mn = fmaxf(mrow[g][j], pmax[j]);
        resc[j] = __expf(mrow[g][j] - mn);
        mrow[g][j] = mn;
      }
#pragma unroll
      for (int nb = 0; nb < 4; nb++)
#pragma unroll
        for (int j = 0; j < 4; j++)
          sf[nb][j] = __expf(sf[nb][j] - mrow[g][j]);
#pragma unroll
      for (int nb = 0; nb < 4; nb++)
#pragma unroll
        for (int j = 0; j < 4; j++) o[g][nb][j] *= resc[j];

#pragma unroll
      for (int nb = 0; nb < 4; nb++) {
        const int ck = nb * 16 + rr;
        const int ss = ck >> 3;
#pragma unroll
        for (int j = 0; j < 4; j++) {
          const int rq = sg * 4 + j;
          Ps[w][rq][(ss ^ (rq & 7)) * 8 + (ck & 7)] = f2bf(sf[nb][j]);
        }
      }
      f32x4 lacc = f32x4{0.f, 0.f, 0.f, 0.f};
#pragma unroll
      for (int ks = 0; ks < 2; ks++) {
        short8 pf = *(const short8*)&Ps[w][rr][((ks * 4 + sg) ^ (rr & 7)) * 8];
        lacc = mfma16(pf, ones8, lacc);   // rowsum(P) in the matrix pipe
#pragma unroll
        for (int nb = 0; nb < 4; nb++) {
          const int dh = nb * 16 + rr;
          short8 vf = *(const short8*)&Vt[dh][((ks * 4 + sg) ^ (dh & 7)) * 8];
          o[g][nb] = mfma16(pf, vf, o[g][nb]);
        }
      }
#pragma unroll
      for (int j = 0; j < 4; j++) lrow[g][j] = lrow[g][j] * resc[j] + lacc[j];
    }
  }

#pragma unroll
  for (int g = 0; g < 2; g++) {
    const size_t orow0 = (size_t)bb * NB_S + qrow_base + g * 16;
#pragma unroll
    for (int nb = 0; nb < 4; nb++)
#pragma unroll
      for (int j = 0; j < 4; j++) {
        const float v = o[g][nb][j] / lrow[g][j];
        out[(orow0 + sg * 4 + j) * NB_D + hh * 64 + nb * 16 + rr] = f2bf(v);
      }
  }
}

// ---------------------------------------------------------------------------
// Head stage 2: out(8176,30) = hbuf(.,100) @ Wh2(100,30) + bh2, fp32.
// ---------------------------------------------------------------------------
__global__ __launch_bounds__(256) void head2_kernel(
    const float* __restrict__ hbuf, const float* __restrict__ Wh2,
    const float* __restrict__ bh2, float* __restrict__ outp) {
  __shared__ float hs[8][NB_HID];
  const int g0 = blockIdx.x * 8;
  for (int idx = threadIdx.x; idx < 8 * NB_HID; idx += 256) {
    const int r = idx / NB_HID, k = idx - r * NB_HID;
    const int gt = g0 + r;
    const int b = gt / NB_T, tt = gt - b * NB_T;
    hs[r][k] = hbuf[(size_t)(b * NB_S + 1 + tt) * 128 + k];
  }
  __syncthreads();
  const int r = threadIdx.x >> 5, c = threadIdx.x & 31;
  if (c < NB_OUT) {
    float acc = bh2[c];
#pragma unroll
    for (int k = 0; k < NB_HID; k++) acc += hs[r][k] * Wh2[k * NB_OUT + c];
    outp[(size_t)(g0 + r) * NB_OUT + c] = acc;
  }
}

// ---------------------------------------------------------------------------
extern "C" void kernel_launch(void* const* d_in, const int* in_sizes, int n_in,
                              void* d_out, int out_size, void* d_ws, size_t ws_size,
                              hipStream_t stream) {
  const float* states = (const float*)d_in[0];
  const float* goals  = (const float*)d_in[1];
  const float* Wtok   = (const float*)d_in[2];
  const float* btok   = (const float*)d_in[3];
  const float* pos    = (const float*)d_in[4];
  const float* ln1_g  = (const float*)d_in[5];
  const float* ln1_b  = (const float*)d_in[6];
  const float* Wq     = (const float*)d_in[7];
  const float* bq     = (const float*)d_in[8];
  const float* Wk     = (const float*)d_in[9];
  const float* bk     = (const float*)d_in[10];
  const float* Wv     = (const float*)d_in[11];
  const float* bv     = (const float*)d_in[12];
  const float* Wp     = (const float*)d_in[13];
  const float* bp     = (const float*)d_in[14];
  const float* ln2_g  = (const float*)d_in[15];
  const float* ln2_b  = (const float*)d_in[16];
  const float* Wm1    = (const float*)d_in[17];
  const float* bm1    = (const float*)d_in[18];
  const float* Wm2    = (const float*)d_in[19];
  const float* bm2    = (const float*)d_in[20];
  const float* lnf_g  = (const float*)d_in[21];
  const float* lnf_b  = (const float*)d_in[22];
  const float* Wh1    = (const float*)d_in[23];
  const float* bh1    = (const float*)d_in[24];
  const float* Wh2    = (const float*)d_in[25];
  const float* bh2    = (const float*)d_in[26];

  char* wsp = (char*)d_ws;
  size_t off = 0;
  auto carve = [&](size_t bytes) -> char* {
    char* p = wsp + off;
    off += (bytes + 1023) & ~(size_t)1023;
    return p;
  };
  short* Wqkv_t = (short*)carve((size_t)NB_L * 3 * NB_D * NB_D * 2);  // (l, 3072, 1024)
  short* Wp_t   = (short*)carve((size_t)NB_L * NB_D * NB_D * 2);
  short* Wm1_t  = (short*)carve((size_t)NB_L * NB_DFF * NB_D * 2);
  short* Wm2_t  = (short*)carve((size_t)NB_L * NB_D * NB_DFF * 2);
  float* x      = (float*)carve((size_t)NB_M * NB_D * 4);
  short* h      = (short*)carve((size_t)NB_M * NB_D * 2);
  short* qkvb   = (short*)carve((size_t)NB_M * QKV_S * 2);
  short* mlp    = (short*)carve((size_t)NB_M * NB_DFF * 2);
  short* Wh1t   = (short*)carve((size_t)128 * NB_D * 2);
  float* bh1p   = (float*)carve(128 * 4);
  float* bqkv   = (float*)carve((size_t)NB_L * QKV_S * 4);
  short* attout = mlp;           // alias: dead before mlp is written
  float* hbuf   = (float*)qkvb;  // alias: qkv dead after last attention

  const dim3 thr(256);
  const size_t DD = (size_t)NB_D * NB_D;
  const size_t DF = (size_t)NB_D * NB_DFF;

  tconv2_kernel<<<dim3(16, 16, NB_L), thr, 0, stream>>>(Wq, Wqkv_t + 0 * DD, NB_D, NB_D, DD, 3 * DD);
  tconv2_kernel<<<dim3(16, 16, NB_L), thr, 0, stream>>>(Wk, Wqkv_t + 1 * DD, NB_D, NB_D, DD, 3 * DD);
  tconv2_kernel<<<dim3(16, 16, NB_L), thr, 0, stream>>>(Wv, Wqkv_t + 2 * DD, NB_D, NB_D, DD, 3 * DD);
  tconv2_kernel<<<dim3(16, 16, NB_L), thr, 0, stream>>>(Wp, Wp_t, NB_D, NB_D, DD, DD);
  tconv2_kernel<<<dim3(64, 16, NB_L), thr, 0, stream>>>(Wm1, Wm1_t, NB_D, NB_DFF, DF, DF);
  tconv2_kernel<<<dim3(16, 64, NB_L), thr, 0, stream>>>(Wm2, Wm2_t, NB_DFF, NB_D, DF, DF);
  whead_prep<<<512, thr, 0, stream>>>(Wh1, bh1, Wh1t, bh1p);
  qkvbias_prep<<<96, thr, 0, stream>>>(bq, bk, bv, bqkv);

  embed2_kernel<<<NB_M / 8, thr, 0, stream>>>(states, goals, Wtok, btok, pos, x);

  for (int l = 0; l < NB_L; l++) {
    ln_wave<short><<<NB_M / 4, thr, 0, stream>>>(x, ln1_g + l * NB_D, ln1_b + l * NB_D, h);
    gemmv4<256, QKV_S, NB_D, 0, false, short><<<768, thr, 0, stream>>>(
        h, Wqkv_t + (size_t)l * 3 * DD, bqkv + (size_t)l * QKV_S, nullptr, qkvb);
    attn2_kernel<<<dim3(NB_S / 128, NB_H, NB_B), thr, 0, stream>>>(qkvb, attout);
    gemmv4<128, NB_D, NB_D, 0, true, float><<<512, thr, 0, stream>>>(
        attout, Wp_t + (size_t)l * DD, bp + l * NB_D, x, x);
    ln_wave<short><<<NB_M / 4, thr, 0, stream>>>(x, ln2_g + l * NB_D, ln2_b + l * NB_D, h);
    gemmv4<256, NB_DFF, NB_D, 1, false, short><<<1024, thr, 0, stream>>>(
        h, Wm1_t + (size_t)l * DF, bm1 + l * NB_DFF, nullptr, mlp);
    gemmv4<128, NB_D, NB_DFF, 0, true, float><<<512, thr, 0, stream>>>(
        mlp, Wm2_t + (size_t)l * DF, bm2 + l * NB_D, x, x);
  }

  ln_wave<short><<<NB_M / 4, thr, 0, stream>>>(x, lnf_g, lnf_b, h);
  gemm_bt<2, false, float><<<dim3(1, NB_M / 128), thr, 0, stream>>>(
      h, Wh1t, bh1p, nullptr, hbuf, 128, NB_D);
  head2_kernel<<<NB_M / 8, thr, 0, stream>>>(hbuf, Wh2, bh2, (float*)d_out);
}